// Round 5
// baseline (268.087 us; speedup 1.0000x reference)
//
#include <hip/hip_runtime.h>
#include <math.h>

#define DIM 128
#define P_POS 3
#define N_NEG 63
#define SCALE 16.0f

typedef float floatx2 __attribute__((ext_vector_type(2)));

#if defined(__has_builtin)
#if __has_builtin(__builtin_elementwise_fma)
#define HAVE_EFMA 1
#endif
#endif

__device__ __forceinline__ floatx2 pkfma(floatx2 a, floatx2 b, floatx2 c) {
#ifdef HAVE_EFMA
    return __builtin_elementwise_fma(a, b, c);
#else
    floatx2 r;
    r.x = fmaf(a.x, b.x, c.x);
    r.y = fmaf(a.y, b.y, c.y);
    return r;
#endif
}

__device__ __forceinline__ float wave_reduce_sum(float v) {
#pragma unroll
    for (int off = 32; off > 0; off >>= 1) v += __shfl_xor(v, off, 64);
    return v;
}
__device__ __forceinline__ float g16_reduce(float v) {
#pragma unroll
    for (int off = 8; off > 0; off >>= 1) v += __shfl_xor(v, off, 64);
    return v;
}
__device__ __forceinline__ float g32_reduce(float v) {
#pragma unroll
    for (int off = 16; off > 0; off >>= 1) v += __shfl_xor(v, off, 64);
    return v;
}

// Normalize each ids_fut row, scale by 16, pack to fp8 e4m3 (proven, round 3).
__global__ __launch_bounds__(256) void prep_fp8_kernel(const float* __restrict__ fut,
                                                       unsigned* __restrict__ futq,
                                                       int nrows) {
    int half = threadIdx.x >> 5;
    int l = threadIdx.x & 31;
    int row = blockIdx.x * 8 + half;
    if (row >= nrows) return;
    float4 x = *reinterpret_cast<const float4*>(fut + (size_t)row * DIM + l * 4);
    float ss = x.x * x.x;
    ss = fmaf(x.y, x.y, ss);
    ss = fmaf(x.z, x.z, ss);
    ss = fmaf(x.w, x.w, ss);
    ss = g32_reduce(ss);
    float r = (ss > 0.f) ? rsqrtf(ss) * SCALE : 0.f;
    int w = __builtin_amdgcn_cvt_pk_fp8_f32(x.x * r, x.y * r, 0, false);
    w = __builtin_amdgcn_cvt_pk_fp8_f32(x.z * r, x.w * r, w, true);
    futq[(size_t)row * 32 + l] = (unsigned)w;
}

// One wave per anchor; 4 groups x 16 lanes; packed-f32 dots; folded final reduce.
__global__ __launch_bounds__(256) void idloss_fp8p_kernel(
    const float* __restrict__ hist, const int* __restrict__ anchor_idx,
    const int* __restrict__ pos_idx, const int* __restrict__ neg_idx,
    const uint2* __restrict__ futq, float* __restrict__ partials,
    unsigned* __restrict__ counter, float* __restrict__ out, int nblocks) {
    __shared__ float smem[4];
    __shared__ float rbuf[256];
    __shared__ int lastflag;
    const int wave = threadIdx.x >> 6;
    const int lane = threadIdx.x & 63;
    const int m = __builtin_amdgcn_readfirstlane(blockIdx.x * 4 + wave);
    const int g = lane >> 4;
    const int t = lane & 15;

    // per-lane coalesced neg-index load (broadcast via shfl below)
    int nidx = (lane < N_NEG) ? neg_idx[m * N_NEG + lane] : 0;

    // wave-uniform scalar loads (SMEM pipe, off the VALU)
    const int aidx = anchor_idx[m];
    const int p0 = pos_idx[m * P_POS + 0];
    const int p1 = pos_idx[m * P_POS + 1];
    const int p2 = pos_idx[m * P_POS + 2];
    int pidx = (g == 1) ? p1 : (g == 2) ? p2 : p0;

    // anchor row: elements [8t, 8t+8), replicated across the 4 groups
    const float4* ap =
        reinterpret_cast<const float4*>(hist + (size_t)aidx * DIM + t * 8);
    float4 a0 = ap[0], a1 = ap[1];
    float ss = a0.x * a0.x;
    ss = fmaf(a0.y, a0.y, ss);
    ss = fmaf(a0.z, a0.z, ss);
    ss = fmaf(a0.w, a0.w, ss);
    ss = fmaf(a1.x, a1.x, ss);
    ss = fmaf(a1.y, a1.y, ss);
    ss = fmaf(a1.z, a1.z, ss);
    ss = fmaf(a1.w, a1.w, ss);
    ss = g16_reduce(ss);
    float rna = (ss > 0.f) ? rsqrtf(ss) * (1.0f / SCALE) : 0.f;
    floatx2 av0, av1, av2, av3;
    av0.x = a0.x * rna; av0.y = a0.y * rna;
    av1.x = a0.z * rna; av1.y = a0.w * rna;
    av2.x = a1.x * rna; av2.y = a1.y * rna;
    av3.x = a1.z * rna; av3.y = a1.w * rna;

    // broadcast neg indices in-register
    int js[16];
#pragma unroll
    for (int k = 0; k < 16; ++k) js[k] = __shfl(nidx, 4 * k + g, 64);

    // burst-issue all gathers; mask invalid lanes by zeroing data (fp8 0 -> 0.0f)
    uint2 vp = futq[(size_t)pidx * 16 + t];
    if (g >= P_POS) { vp.x = 0u; vp.y = 0u; }
    uint2 vs[16];
#pragma unroll
    for (int k = 0; k < 16; ++k) {
        vs[k] = futq[(size_t)js[k] * 16 + t];
        if (4 * k + g >= N_NEG) { vs[k].x = 0u; vs[k].y = 0u; }
    }

    // packed dots; two interleaved accumulators to shorten dep chains
    floatx2 na = {0.f, 0.f}, nb = {0.f, 0.f};
#pragma unroll
    for (int k = 0; k < 16; ++k) {
        uint2 v = vs[k];
        na = pkfma(__builtin_amdgcn_cvt_pk_f32_fp8(v.x, false), av0, na);
        nb = pkfma(__builtin_amdgcn_cvt_pk_f32_fp8(v.x, true), av1, nb);
        na = pkfma(__builtin_amdgcn_cvt_pk_f32_fp8(v.y, false), av2, na);
        nb = pkfma(__builtin_amdgcn_cvt_pk_f32_fp8(v.y, true), av3, nb);
    }
    floatx2 pa = {0.f, 0.f};
    pa = pkfma(__builtin_amdgcn_cvt_pk_f32_fp8(vp.x, false), av0, pa);
    pa = pkfma(__builtin_amdgcn_cvt_pk_f32_fp8(vp.x, true), av1, pa);
    pa = pkfma(__builtin_amdgcn_cvt_pk_f32_fp8(vp.y, false), av2, pa);
    pa = pkfma(__builtin_amdgcn_cvt_pk_f32_fp8(vp.y, true), av3, pa);

    float accn = wave_reduce_sum(na.x + na.y + nb.x + nb.y);
    float accp = wave_reduce_sum(pa.x + pa.y);

    if (lane == 0) {
        float sp = accp + (float)P_POS;
        float sn = accn + (float)N_NEG;
        smem[wave] = -logf(sp / (sp + sn));
    }
    __syncthreads();
    if (threadIdx.x == 0) {
        partials[blockIdx.x] = smem[0] + smem[1] + smem[2] + smem[3];
        __threadfence();
        unsigned old = __hip_atomic_fetch_add(counter, 1u, __ATOMIC_ACQ_REL,
                                              __HIP_MEMORY_SCOPE_AGENT);
        lastflag = (old == (unsigned)(nblocks - 1)) ? 1 : 0;
    }
    __syncthreads();
    if (lastflag) {
        __threadfence();
        float a = 0.f;
        for (int i = threadIdx.x; i < nblocks; i += 256) a += partials[i];
        rbuf[threadIdx.x] = a;
        __syncthreads();
#pragma unroll
        for (int s = 128; s > 0; s >>= 1) {
            if ((int)threadIdx.x < s) rbuf[threadIdx.x] += rbuf[threadIdx.x + s];
            __syncthreads();
        }
        if (threadIdx.x == 0) out[0] = rbuf[0];
    }
}

extern "C" void kernel_launch(void* const* d_in, const int* in_sizes, int n_in,
                              void* d_out, int out_size, void* d_ws, size_t ws_size,
                              hipStream_t stream) {
    const float* fut  = (const float*)d_in[0];
    const float* hist = (const float*)d_in[1];
    const int* anchor_idx = (const int*)d_in[2];
    const int* pos_idx    = (const int*)d_in[3];
    const int* neg_idx    = (const int*)d_in[4];

    int N = in_sizes[0] / DIM;   // 66560
    int M = in_sizes[2];         // 16384
    int main_blocks = M / 4;     // 4096

    size_t futq_bytes = (size_t)N * 32 * sizeof(unsigned);   // fp8 table, 128 B/row
    unsigned* futq = (unsigned*)d_ws;
    float* partials = (float*)((char*)d_ws + futq_bytes);
    unsigned* counter = (unsigned*)(partials + main_blocks);

    hipMemsetAsync(counter, 0, sizeof(unsigned), stream);
    int prep_blocks = (N + 7) / 8;
    prep_fp8_kernel<<<prep_blocks, 256, 0, stream>>>(fut, futq, N);
    idloss_fp8p_kernel<<<main_blocks, 256, 0, stream>>>(hist, anchor_idx, pos_idx,
                                                        neg_idx, (const uint2*)futq,
                                                        partials, counter,
                                                        (float*)d_out, main_blocks);
}

// Round 6
// 34.120 us; speedup vs baseline: 7.8571x; 7.8571x over previous
//
#include <hip/hip_runtime.h>
#include <math.h>

#define DIM 128
#define P_POS 3
#define N_NEG 63
#define SCALE 16.0f

typedef float floatx2 __attribute__((ext_vector_type(2)));

#if defined(__has_builtin)
#if __has_builtin(__builtin_elementwise_fma)
#define HAVE_EFMA 1
#endif
#endif

__device__ __forceinline__ floatx2 pkfma(floatx2 a, floatx2 b, floatx2 c) {
#ifdef HAVE_EFMA
    return __builtin_elementwise_fma(a, b, c);
#else
    floatx2 r;
    r.x = fmaf(a.x, b.x, c.x);
    r.y = fmaf(a.y, b.y, c.y);
    return r;
#endif
}

__device__ __forceinline__ float wave_reduce_sum(float v) {
#pragma unroll
    for (int off = 32; off > 0; off >>= 1) v += __shfl_xor(v, off, 64);
    return v;
}
__device__ __forceinline__ float g16_reduce(float v) {
#pragma unroll
    for (int off = 8; off > 0; off >>= 1) v += __shfl_xor(v, off, 64);
    return v;
}
__device__ __forceinline__ float g32_reduce(float v) {
#pragma unroll
    for (int off = 16; off > 0; off >>= 1) v += __shfl_xor(v, off, 64);
    return v;
}

// Normalize each ids_fut row, scale by 16, pack to fp8 e4m3 (proven, round 3).
__global__ __launch_bounds__(256) void prep_fp8_kernel(const float* __restrict__ fut,
                                                       unsigned* __restrict__ futq,
                                                       int nrows) {
    int half = threadIdx.x >> 5;
    int l = threadIdx.x & 31;
    int row = blockIdx.x * 8 + half;
    if (row >= nrows) return;
    float4 x = *reinterpret_cast<const float4*>(fut + (size_t)row * DIM + l * 4);
    float ss = x.x * x.x;
    ss = fmaf(x.y, x.y, ss);
    ss = fmaf(x.z, x.z, ss);
    ss = fmaf(x.w, x.w, ss);
    ss = g32_reduce(ss);
    float r = (ss > 0.f) ? rsqrtf(ss) * SCALE : 0.f;
    int w = __builtin_amdgcn_cvt_pk_fp8_f32(x.x * r, x.y * r, 0, false);
    w = __builtin_amdgcn_cvt_pk_fp8_f32(x.z * r, x.w * r, w, true);
    futq[(size_t)row * 32 + l] = (unsigned)w;
}

// One wave per anchor; 4 groups x 16 lanes; packed-f32 dots; burst gathers.
// NO device-scope fences/atomics (round-5 lesson: agent-scope acq-rel per
// block forces per-XCD L2 writeback/invalidate -> 7x regression).
__global__ __launch_bounds__(256) void idloss_fp8p_kernel(
    const float* __restrict__ hist, const int* __restrict__ anchor_idx,
    const int* __restrict__ pos_idx, const int* __restrict__ neg_idx,
    const uint2* __restrict__ futq, float* __restrict__ partials) {
    __shared__ float smem[4];
    const int wave = threadIdx.x >> 6;
    const int lane = threadIdx.x & 63;
    const int m = __builtin_amdgcn_readfirstlane(blockIdx.x * 4 + wave);
    const int g = lane >> 4;
    const int t = lane & 15;

    // per-lane coalesced neg-index load (broadcast via shfl below)
    int nidx = (lane < N_NEG) ? neg_idx[m * N_NEG + lane] : 0;

    // wave-uniform scalar loads (SMEM pipe, off the VALU)
    const int aidx = anchor_idx[m];
    const int p0 = pos_idx[m * P_POS + 0];
    const int p1 = pos_idx[m * P_POS + 1];
    const int p2 = pos_idx[m * P_POS + 2];
    int pidx = (g == 1) ? p1 : (g == 2) ? p2 : p0;

    // anchor row: elements [8t, 8t+8), replicated across the 4 groups
    const float4* ap =
        reinterpret_cast<const float4*>(hist + (size_t)aidx * DIM + t * 8);
    float4 a0 = ap[0], a1 = ap[1];
    float ss = a0.x * a0.x;
    ss = fmaf(a0.y, a0.y, ss);
    ss = fmaf(a0.z, a0.z, ss);
    ss = fmaf(a0.w, a0.w, ss);
    ss = fmaf(a1.x, a1.x, ss);
    ss = fmaf(a1.y, a1.y, ss);
    ss = fmaf(a1.z, a1.z, ss);
    ss = fmaf(a1.w, a1.w, ss);
    ss = g16_reduce(ss);
    float rna = (ss > 0.f) ? rsqrtf(ss) * (1.0f / SCALE) : 0.f;
    floatx2 av0, av1, av2, av3;
    av0.x = a0.x * rna; av0.y = a0.y * rna;
    av1.x = a0.z * rna; av1.y = a0.w * rna;
    av2.x = a1.x * rna; av2.y = a1.y * rna;
    av3.x = a1.z * rna; av3.y = a1.w * rna;

    // broadcast neg indices in-register
    int js[16];
#pragma unroll
    for (int k = 0; k < 16; ++k) js[k] = __shfl(nidx, 4 * k + g, 64);

    // burst-issue all gathers; mask invalid lanes by zeroing data (fp8 0 -> 0.0f)
    uint2 vp = futq[(size_t)pidx * 16 + t];
    if (g >= P_POS) { vp.x = 0u; vp.y = 0u; }
    uint2 vs[16];
#pragma unroll
    for (int k = 0; k < 16; ++k) {
        vs[k] = futq[(size_t)js[k] * 16 + t];
        if (4 * k + g >= N_NEG) { vs[k].x = 0u; vs[k].y = 0u; }
    }

    // packed dots; two interleaved accumulators to shorten dep chains
    floatx2 na = {0.f, 0.f}, nb = {0.f, 0.f};
#pragma unroll
    for (int k = 0; k < 16; ++k) {
        uint2 v = vs[k];
        na = pkfma(__builtin_amdgcn_cvt_pk_f32_fp8(v.x, false), av0, na);
        nb = pkfma(__builtin_amdgcn_cvt_pk_f32_fp8(v.x, true), av1, nb);
        na = pkfma(__builtin_amdgcn_cvt_pk_f32_fp8(v.y, false), av2, na);
        nb = pkfma(__builtin_amdgcn_cvt_pk_f32_fp8(v.y, true), av3, nb);
    }
    floatx2 pa = {0.f, 0.f};
    pa = pkfma(__builtin_amdgcn_cvt_pk_f32_fp8(vp.x, false), av0, pa);
    pa = pkfma(__builtin_amdgcn_cvt_pk_f32_fp8(vp.x, true), av1, pa);
    pa = pkfma(__builtin_amdgcn_cvt_pk_f32_fp8(vp.y, false), av2, pa);
    pa = pkfma(__builtin_amdgcn_cvt_pk_f32_fp8(vp.y, true), av3, pa);

    float accn = wave_reduce_sum(na.x + na.y + nb.x + nb.y);
    float accp = wave_reduce_sum(pa.x + pa.y);

    if (lane == 0) {
        float sp = accp + (float)P_POS;
        float sn = accn + (float)N_NEG;
        smem[wave] = -logf(sp / (sp + sn));
    }
    __syncthreads();
    if (threadIdx.x == 0)
        partials[blockIdx.x] = smem[0] + smem[1] + smem[2] + smem[3];
}

__global__ __launch_bounds__(256) void reduce_kernel(const float* __restrict__ partials,
                                                     float* __restrict__ out, int n) {
    __shared__ float smem[256];
    float acc = 0.f;
    for (int i = threadIdx.x; i < n; i += 256) acc += partials[i];
    smem[threadIdx.x] = acc;
    __syncthreads();
#pragma unroll
    for (int s = 128; s > 0; s >>= 1) {
        if ((int)threadIdx.x < s) smem[threadIdx.x] += smem[threadIdx.x + s];
        __syncthreads();
    }
    if (threadIdx.x == 0) out[0] = smem[0];
}

extern "C" void kernel_launch(void* const* d_in, const int* in_sizes, int n_in,
                              void* d_out, int out_size, void* d_ws, size_t ws_size,
                              hipStream_t stream) {
    const float* fut  = (const float*)d_in[0];
    const float* hist = (const float*)d_in[1];
    const int* anchor_idx = (const int*)d_in[2];
    const int* pos_idx    = (const int*)d_in[3];
    const int* neg_idx    = (const int*)d_in[4];

    int N = in_sizes[0] / DIM;   // 66560
    int M = in_sizes[2];         // 16384
    int main_blocks = M / 4;     // 4096

    size_t futq_bytes = (size_t)N * 32 * sizeof(unsigned);   // fp8 table, 128 B/row
    unsigned* futq = (unsigned*)d_ws;
    float* partials = (float*)((char*)d_ws + futq_bytes);

    int prep_blocks = (N + 7) / 8;
    prep_fp8_kernel<<<prep_blocks, 256, 0, stream>>>(fut, futq, N);
    idloss_fp8p_kernel<<<main_blocks, 256, 0, stream>>>(hist, anchor_idx, pos_idx,
                                                        neg_idx, (const uint2*)futq,
                                                        partials);
    reduce_kernel<<<1, 256, 0, stream>>>(partials, (float*)d_out, main_blocks);
}